// Round 14
// baseline (180.920 us; speedup 1.0000x reference)
//
#include <hip/hip_runtime.h>
#include <hip/hip_bf16.h>

#define HEADS 8
#define HID   64
#define EMB   512
#define HH    512
#define LOCAL 64
#define BS    4
#define NSEQ  2048
#define ROWS  (BS*NSEQ)   // 8192

typedef __attribute__((ext_vector_type(8))) short short8;   // 8 bf16 = 4 VGPRs
typedef __attribute__((ext_vector_type(4))) float f32x4;

__device__ __forceinline__ ushort f2b(float f) {
    union { float f; unsigned u; } c; c.f = f;
    return (ushort)((c.u + 0x7FFFu + ((c.u >> 16) & 1u)) >> 16);
}
__device__ __forceinline__ float b2f(ushort u) {
    union { unsigned u; float f; } c; c.u = ((unsigned)u) << 16; return c.f;
}

#define MFMA16(a, b, c) __builtin_amdgcn_mfma_f32_16x16x32_bf16(a, b, c, 0, 0, 0)

// ---------------------------------------------------------------------------
// prep: blocks [0,2048) convert x -> bf16 (2 float4/thread); blocks
// [2048,2304) transpose the four weight matrices to n-major bf16 (64x64).
// ---------------------------------------------------------------------------
__global__ __launch_bounds__(256) void prep(
    const float* __restrict__ x,
    const float* __restrict__ w0, const float* __restrict__ w1,
    const float* __restrict__ w2, const float* __restrict__ w3,
    ushort* __restrict__ xb, ushort* __restrict__ dst012,
    ushort* __restrict__ dst3)
{
    const int id = blockIdx.x;
    if (id < 2048) {
        const int j = id * 256 + threadIdx.x;
#pragma unroll
        for (int half = 0; half < 2; ++half) {
            const int i = j + half * 524288;
            float4 f = ((const float4*)x)[i];
            ushort4 u;
            u.x = f2b(f.x); u.y = f2b(f.y); u.z = f2b(f.z); u.w = f2b(f.w);
            ((ushort4*)xb)[i] = u;
        }
    } else {
        __shared__ float s[64][68];
        const int id2 = id - 2048;
        const int z = id2 >> 6, t = id2 & 63;
        const float* src = (z == 0) ? w0 : (z == 1) ? w1 : (z == 2) ? w2 : w3;
        ushort* dst = (z < 3) ? dst012 + (size_t)z * 512 * 512 : dst3;
        const int n0 = (t & 7) * 64, k0 = (t >> 3) * 64;
        const int tx = threadIdx.x & 15, ty = threadIdx.x >> 4;
#pragma unroll
        for (int p = 0; p < 4; ++p)
            *(float4*)&s[ty + 16 * p][tx * 4] =
                *(const float4*)&src[(size_t)(k0 + ty + 16 * p) * 512 + n0 + tx * 4];
        __syncthreads();
#pragma unroll
        for (int p = 0; p < 4; ++p) {
            ushort4 u;
            u.x = f2b(s[tx * 4 + 0][ty + 16 * p]);
            u.y = f2b(s[tx * 4 + 1][ty + 16 * p]);
            u.z = f2b(s[tx * 4 + 2][ty + 16 * p]);
            u.w = f2b(s[tx * 4 + 3][ty + 16 * p]);
            *(ushort4*)&dst[(size_t)(n0 + ty + 16 * p) * 512 + k0 + tx * 4] = u;
        }
    }
}

// ---------------------------------------------------------------------------
// QKV GEMM, DIRECT-LOAD: one 64-thread wave per 64x64 output tile.  All
// MFMA fragments load straight from global (A row-major, Bt n-major -> 16B
// contiguous frags); no LDS staging, no barriers.  Grid 3072, lin =
// col*128 + row -> A-stripe sharers co-XCD (lin%8 = row%8).  Epilogue:
// same-wave LDS repack -> 16B stores; q,k scaled 0.125; V also transposed
// into vT[((b*8+h)*64+d)*2048 + n].
// ---------------------------------------------------------------------------
__global__ __launch_bounds__(64) void gemm_qkv(
    const ushort* __restrict__ A, const ushort* __restrict__ Bt,
    ushort* __restrict__ oq, ushort* __restrict__ ok, ushort* __restrict__ ov,
    ushort* __restrict__ vT)
{
    const int lin  = blockIdx.x;
    const int rowW = (lin & 127) * 64;   // 128 row tiles (M=8192)
    const int colW = (lin >> 7) * 64;    // 24 col tiles  (N=1536)
    const int lane = threadIdx.x, l15 = lane & 15, quad = lane >> 4;

    __shared__ ushort T[64 * 72];        // epilogue repack (9 KB)

    f32x4 acc[4][4] = {};
    const ushort* aB = A  + (size_t)(rowW + l15) * 512 + quad * 8;
    const ushort* bB = Bt + (size_t)(colW + l15) * 512 + quad * 8;

#pragma unroll 2
    for (int kt = 0; kt < 512; kt += 32) {
        short8 af[4], bf[4];
#pragma unroll
        for (int mi = 0; mi < 4; ++mi)
            af[mi] = *(const short8*)(aB + (size_t)mi * 16 * 512 + kt);
#pragma unroll
        for (int ni = 0; ni < 4; ++ni)
            bf[ni] = *(const short8*)(bB + (size_t)ni * 16 * 512 + kt);
#pragma unroll
        for (int mi = 0; mi < 4; ++mi)
#pragma unroll
            for (int ni = 0; ni < 4; ++ni)
                acc[mi][ni] = MFMA16(af[mi], bf[ni], acc[mi][ni]);
    }

    // ---- epilogue: C-layout -> LDS (stride 72, 16B-aligned rows) ----
    const int sec = colW >> 9;           // 0=q 1=k 2=v
    const float s = (sec == 2) ? 1.0f : 0.125f;
    const int cb = colW & 511;
#pragma unroll
    for (int mi = 0; mi < 4; ++mi)
#pragma unroll
        for (int ni = 0; ni < 4; ++ni)
#pragma unroll
            for (int r = 0; r < 4; ++r)
                T[(mi * 16 + quad * 4 + r) * 72 + ni * 16 + l15] =
                    f2b(acc[mi][ni][r] * s);
    // same-wave LDS: compiler inserts lgkmcnt waits; no barrier needed.
    ushort* dst = (sec == 0) ? oq : (sec == 1) ? ok : ov;
#pragma unroll
    for (int u = 0; u < 8; ++u)          // lane = row, 8 x 16B per row
        *(short8*)&dst[(size_t)(rowW + lane) * HH + cb + u * 8] =
            *(const short8*)&T[lane * 72 + u * 8];
    if (sec == 2) {
        const int hh = cb >> 6;          // wave's 64 cols = one head
        const int bb = rowW >> 11;
        const int nn0 = rowW & 2047;
        ushort* vbase = vT + ((size_t)((bb * HEADS + hh) * HID) + lane) * NSEQ + nn0;
#pragma unroll
        for (int u = 0; u < 8; ++u) {    // lane = d; gather col, store 16B
            short8 val;
#pragma unroll
            for (int j = 0; j < 8; ++j) val[j] = T[(u * 8 + j) * 72 + lane];
            *(short8*)(vbase + u * 8) = val;
        }
    }
}

// ---------------------------------------------------------------------------
// Unify GEMM, DIRECT-LOAD: one wave per 64x64 tile, +bias, fp32 out.
// Grid 1024, lin = col*128 + row (co-XCD A-stripes).
// ---------------------------------------------------------------------------
__global__ __launch_bounds__(64) void gemm_unify(
    const ushort* __restrict__ A, const ushort* __restrict__ Bt,
    const float* __restrict__ bias, float* __restrict__ out)
{
    const int lin  = blockIdx.x;
    const int rowW = (lin & 127) * 64;   // 128 row tiles
    const int colW = (lin >> 7) * 64;    // 8 col tiles (N=512)
    const int lane = threadIdx.x, l15 = lane & 15, quad = lane >> 4;

    __shared__ float Tf[64 * 68];        // 17 KB; stride 68 -> 16B-aligned rows

    f32x4 acc[4][4] = {};
    const ushort* aB = A  + (size_t)(rowW + l15) * 512 + quad * 8;
    const ushort* bB = Bt + (size_t)(colW + l15) * 512 + quad * 8;

#pragma unroll 2
    for (int kt = 0; kt < 512; kt += 32) {
        short8 af[4], bf[4];
#pragma unroll
        for (int mi = 0; mi < 4; ++mi)
            af[mi] = *(const short8*)(aB + (size_t)mi * 16 * 512 + kt);
#pragma unroll
        for (int ni = 0; ni < 4; ++ni)
            bf[ni] = *(const short8*)(bB + (size_t)ni * 16 * 512 + kt);
#pragma unroll
        for (int mi = 0; mi < 4; ++mi)
#pragma unroll
            for (int ni = 0; ni < 4; ++ni)
                acc[mi][ni] = MFMA16(af[mi], bf[ni], acc[mi][ni]);
    }

    float bcol[4];
#pragma unroll
    for (int ni = 0; ni < 4; ++ni)
        bcol[ni] = bias[colW + ni * 16 + l15];
#pragma unroll
    for (int mi = 0; mi < 4; ++mi)
#pragma unroll
        for (int ni = 0; ni < 4; ++ni)
#pragma unroll
            for (int r = 0; r < 4; ++r)
                Tf[(mi * 16 + quad * 4 + r) * 68 + ni * 16 + l15] =
                    acc[mi][ni][r] + bcol[ni];
#pragma unroll
    for (int u = 0; u < 16; ++u) {       // 1024 float4 chunks, coalesced
        const int c = u * 64 + lane;
        const int row = c >> 4, ch = c & 15;
        *(float4*)&out[(size_t)(rowW + row) * EMB + colW + ch * 4] =
            *(const float4*)&Tf[row * 68 + ch * 4];
    }
}

// ---------------------------------------------------------------------------
// Kernel B: strided attention in RESIDUE space (unchanged from R10).
// ---------------------------------------------------------------------------
__global__ __launch_bounds__(64) void attn_str(
    const ushort* __restrict__ q, const ushort* __restrict__ k,
    const ushort* __restrict__ v, ushort* __restrict__ obn,
    float* __restrict__ mbuf, float* __restrict__ sbuf)
{
    const int slice = blockIdx.x & 31;     // h + 8*b
    const int r     = blockIdx.x >> 5;     // residue 0..63
    const int h = slice & 7, b = slice >> 3;
    const int lane = threadIdx.x, l15 = lane & 15, quad = lane >> 4;
    const ptrdiff_t rowb = (ptrdiff_t)b * NSEQ;
    const int hb = h * HID;

    __shared__ union {
        struct { ushort Ps[32][40]; ushort Vt[64][40]; } s;
        float Ot[32][66];
    } U;

    {
        const int dg = lane & 7, g = lane >> 3;
#pragma unroll
        for (int p = 0; p < 4; ++p) {
            const int i = p * 8 + g;
            const short8 vv = *(const short8*)(
                v + (rowb + r + 64 * i) * 512 + hb + dg * 8);
#pragma unroll
            for (int e = 0; e < 8; ++e) {
                const int m = (e + dg) & 7;
                U.s.Vt[dg * 8 + m][i] = (ushort)vv[m];
            }
        }
    }
    { ushort4 z = {0, 0, 0, 0}; *(ushort4*)&U.s.Ps[l15][16 + quad * 4] = z; }

    short8 aq[2][2], bk[2][2];
#pragma unroll
    for (int t = 0; t < 2; ++t) {
        const ushort* p = q + (rowb + r + 64 * (t * 16 + l15)) * 512 + hb + quad * 8;
        aq[t][0] = *(const short8*)p;
        aq[t][1] = *(const short8*)(p + 32);
        const ushort* pk = k + (rowb + r + 64 * (t * 16 + l15)) * 512 + hb + quad * 8;
        bk[t][0] = *(const short8*)pk;
        bk[t][1] = *(const short8*)(pk + 32);
    }
    f32x4 s00 = {}, s10 = {}, s11 = {};
    s00 = MFMA16(aq[0][0], bk[0][0], s00); s00 = MFMA16(aq[0][1], bk[0][1], s00);
    s10 = MFMA16(aq[1][0], bk[0][0], s10); s10 = MFMA16(aq[1][1], bk[0][1], s10);
    s11 = MFMA16(aq[1][0], bk[1][0], s11); s11 = MFMA16(aq[1][1], bk[1][1], s11);

    float rsB[2][4];
#pragma unroll
    for (int t = 0; t < 2; ++t)
#pragma unroll
        for (int rg = 0; rg < 4; ++rg) {
            const int i = t * 16 + quad * 4 + rg;
            float v0 = (t == 0) ? s00[rg] : s10[rg];
            float v1 = (t == 1) ? s11[rg] : -1e30f;
            if (l15 > i - 2) v0 = -1e30f;
            if (t == 1 && 16 + l15 > i - 2) v1 = -1e30f;
            float mx = fmaxf(v0, v1);
            mx = fmaxf(mx, __shfl_xor(mx, 1)); mx = fmaxf(mx, __shfl_xor(mx, 2));
            mx = fmaxf(mx, __shfl_xor(mx, 4)); mx = fmaxf(mx, __shfl_xor(mx, 8));
            const float e0 = __expf(v0 - mx);
            const float e1 = (t == 1) ? __expf(v1 - mx) : 0.f;
            float sum = e0 + e1;
            sum += __shfl_xor(sum, 1); sum += __shfl_xor(sum, 2);
            sum += __shfl_xor(sum, 4); sum += __shfl_xor(sum, 8);
            U.s.Ps[i][l15] = f2b(e0);
            if (t == 1) U.s.Ps[i][16 + l15] = f2b(e1);
            rsB[t][rg] = 1.0f / sum;
            if (l15 == 0 && i >= 2) {
                mbuf[(size_t)slice * NSEQ + r + 64 * i] = mx;
                sbuf[(size_t)slice * NSEQ + r + 64 * i] = sum;
            }
        }

    short8 ap[2], bp[4];
#pragma unroll
    for (int t = 0; t < 2; ++t)
        ap[t] = *(const short8*)&U.s.Ps[t * 16 + l15][quad * 8];
#pragma unroll
    for (int nt = 0; nt < 4; ++nt)
        bp[nt] = *(const short8*)&U.s.Vt[nt * 16 + l15][quad * 8];
    f32x4 O[2][4] = {};
#pragma unroll
    for (int t = 0; t < 2; ++t)
#pragma unroll
        for (int nt = 0; nt < 4; ++nt)
            O[t][nt] = MFMA16(ap[t], bp[nt], O[t][nt]);

#pragma unroll
    for (int t = 0; t < 2; ++t)
#pragma unroll
        for (int nt = 0; nt < 4; ++nt)
#pragma unroll
            for (int rg = 0; rg < 4; ++rg)
                U.Ot[t * 16 + quad * 4 + rg][nt * 16 + l15] = O[t][nt][rg] * rsB[t][rg];
    for (int i = 2; i < 32; ++i)
        obn[(rowb + r + 64 * i) * 512 + hb + lane] = f2b(U.Ot[i][lane]);
}

// ---------------------------------------------------------------------------
// Kernel A: local-band attention + flash-merge (R11-proven 16q version).
// ---------------------------------------------------------------------------
struct __align__(16) WaveWS {
    union { ushort Ps[16][112]; float Ot[16][66]; } u;
    float ca[16], cb[16];
};

__global__ __launch_bounds__(64) void attn_band(
    const ushort* __restrict__ q, const ushort* __restrict__ k,
    const ushort* __restrict__ vT, const ushort* __restrict__ obn,
    const float* __restrict__ mbuf, const float* __restrict__ sbuf,
    ushort* __restrict__ o)
{
    const int slice = blockIdx.x & 31;
    const int qidx  = blockIdx.x >> 5;
    const int h = slice & 7, b = slice >> 3;
    const int lane = threadIdx.x;
    const int l15 = lane & 15, quad = lane >> 4;
    const int qw = qidx * 16;
    const int qb = qw >> 6;
    const int band0 = qw - 64;

    __shared__ WaveWS S;

    const ptrdiff_t rowb = (ptrdiff_t)b * NSEQ;
    const int hb = h * HID;

    { ushort4 z = {0, 0, 0, 0}; *(ushort4*)&S.u.Ps[l15][80 + quad * 4] = z; }

    short8 afq[2];
    {
        const ushort* qp = q + (rowb + qw + l15) * 512 + hb + quad * 8;
        afq[0] = *(const short8*)qp;
        afq[1] = *(const short8*)(qp + 32);
    }

    f32x4 accL[5];
#pragma unroll
    for (int kt = 0; kt < 5; ++kt) {
        accL[kt] = (f32x4){0.f, 0.f, 0.f, 0.f};
        const ushort* kp = k + (rowb + band0 + kt * 16 + l15) * 512 + hb + quad * 8;
        const short8 b0 = *(const short8*)kp;
        const short8 b1 = *(const short8*)(kp + 32);
        accL[kt] = MFMA16(afq[0], b0, accL[kt]);
        accL[kt] = MFMA16(afq[1], b1, accL[kt]);
    }

#pragma unroll
    for (int rg = 0; rg < 4; ++rg) {
        const int row16 = quad * 4 + rg;
        float pm[5], mx = -1e30f;
#pragma unroll
        for (int kt = 0; kt < 5; ++kt) {
            const int col = kt * 16 + l15;
            const bool okm = (col >= row16) && (col <= 64 + row16) && (band0 + col >= 0);
            pm[kt] = okm ? accL[kt][rg] : -1e30f;
            mx = fmaxf(mx, pm[kt]);
        }
        mx = fmaxf(mx, __shfl_xor(mx, 1)); mx = fmaxf(mx, __shfl_xor(mx, 2));
        mx = fmaxf(mx, __shfl_xor(mx, 4)); mx = fmaxf(mx, __shfl_xor(mx, 8));
        float sum = 0.f;
#pragma unroll
        for (int kt = 0; kt < 5; ++kt) {
            const float pv = __expf(pm[kt] - mx);
            sum += pv;
            S.u.Ps[row16][kt * 16 + l15] = f2b(pv);
        }
        sum += __shfl_xor(sum, 1); sum += __shfl_xor(sum, 2);
        sum += __shfl_xor(sum, 4); sum += __shfl_xor(sum, 8);
        if (l15 == 0) {
            if (qb >= 2) {
                const float mB = mbuf[(size_t)slice * NSEQ + qw + row16];
                const float sB = sbuf[(size_t)slice * NSEQ + qw + row16];
                const float m  = fmaxf(mx, mB);
                const float eA = __expf(mx - m), eB = __expf(mB - m);
                const float denom = sum * eA + sB * eB;
                S.ca[row16] = eA / denom;
                S.cb[row16] = sB * eB / denom;
            } else {
                S.ca[row16] = 1.0f / sum;
                S.cb[row16] = 0.f;
            }
        }
    }

    f32x4 O[4];
#pragma unroll
    for (int nt = 0; nt < 4; ++nt) O[nt] = (f32x4){0.f, 0.f, 0.f, 0.f};
    const ushort* vtb = vT + ((ptrdiff_t)(b * HEADS + h) * HID) * NSEQ;
#pragma unroll
    for (int ks = 0; ks < 3; ++ks) {
        const short8 ap = *(const short8*)&S.u.Ps[l15][ks * 32 + quad * 8];
#pragma unroll
        for (int nt = 0; nt < 4; ++nt) {
            const short8 bp = *(const short8*)(
                vtb + (ptrdiff_t)(nt * 16 + l15) * NSEQ + band0 + ks * 32 + quad * 8);
            O[nt] = MFMA16(ap, bp, O[nt]);
        }
    }

#pragma unroll
    for (int nt = 0; nt < 4; ++nt)
#pragma unroll
        for (int rg = 0; rg < 4; ++rg)
            S.u.Ot[quad * 4 + rg][nt * 16 + l15] = O[nt][rg];

    if (qb >= 2) {
#pragma unroll 4
        for (int i2 = 0; i2 < 16; ++i2) {
            const ptrdiff_t off = (rowb + qw + i2) * 512 + hb + lane;
            const float val = S.u.Ot[i2][lane] * S.ca[i2] + b2f(obn[off]) * S.cb[i2];
            o[off] = f2b(val);
        }
    } else {
#pragma unroll 4
        for (int i2 = 0; i2 < 16; ++i2) {
            const ptrdiff_t off = (rowb + qw + i2) * 512 + hb + lane;
            o[off] = f2b(S.u.Ot[i2][lane] * S.ca[i2]);
        }
    }
}

// ---------------------------------------------------------------------------
extern "C" void kernel_launch(void* const* d_in, const int* in_sizes, int n_in,
                              void* d_out, int out_size, void* d_ws, size_t ws_size,
                              hipStream_t stream)
{
    // dict order: x, w_keys, w_queries, w_values, w_unify, b_unify (fp32)
    const float* x  = (const float*)d_in[0];
    const float* wk = (const float*)d_in[1];
    const float* wq = (const float*)d_in[2];
    const float* wv = (const float*)d_in[3];
    const float* wu = (const float*)d_in[4];
    const float* bu = (const float*)d_in[5];
    float* out = (float*)d_out;

    // ws: xb 8M | wbt 1.5M | wubt .5M | ob 8M | qb 8M | kb 8M | vT 8M | vb 8M
    //     | obn 8M | mbuf .25M | sbuf .25M
    ushort* xb   = (ushort*)d_ws;
    ushort* wbt  = xb   + (size_t)ROWS * EMB;
    ushort* wubt = wbt  + (size_t)1536 * 512;
    ushort* ob   = wubt + (size_t)512 * 512;
    ushort* qbuf = ob   + (size_t)ROWS * HH;
    ushort* kbuf = qbuf + (size_t)ROWS * HH;
    ushort* vTb  = kbuf + (size_t)ROWS * HH;
    ushort* vbuf = vTb  + (size_t)ROWS * HH;
    ushort* obn  = vbuf + (size_t)ROWS * HH;
    float*  mbuf = (float*)(obn + (size_t)ROWS * HH);
    float*  sbuf = mbuf + (size_t)32 * NSEQ;

    prep<<<2304, 256, 0, stream>>>(x, wq, wk, wv, wu, xb, wbt, wubt);
    gemm_qkv<<<24 * 128, 64, 0, stream>>>(xb, wbt, qbuf, kbuf, vbuf, vTb);
    attn_str<<<64 * 32, 64, 0, stream>>>(qbuf, kbuf, vbuf, obn, mbuf, sbuf);
    attn_band<<<128 * 32, 64, 0, stream>>>(qbuf, kbuf, vTb, obn, mbuf, sbuf, ob);
    gemm_unify<<<8 * 128, 64, 0, stream>>>(ob, wubt, bu, out);
}

// Round 15
// 142.879 us; speedup vs baseline: 1.2662x; 1.2662x over previous
//
#include <hip/hip_runtime.h>
#include <hip/hip_bf16.h>

#define HEADS 8
#define HID   64
#define EMB   512
#define HH    512
#define LOCAL 64
#define BS    4
#define NSEQ  2048
#define ROWS  (BS*NSEQ)   // 8192

typedef __attribute__((ext_vector_type(8))) short short8;   // 8 bf16 = 4 VGPRs
typedef __attribute__((ext_vector_type(4))) float f32x4;

__device__ __forceinline__ ushort f2b(float f) {
    union { float f; unsigned u; } c; c.f = f;
    return (ushort)((c.u + 0x7FFFu + ((c.u >> 16) & 1u)) >> 16);
}
__device__ __forceinline__ float b2f(ushort u) {
    union { unsigned u; float f; } c; c.u = ((unsigned)u) << 16; return c.f;
}

__device__ __forceinline__ void async16(const void* g, void* l) {
    __builtin_amdgcn_global_load_lds(
        (const __attribute__((address_space(1))) void*)g,
        (__attribute__((address_space(3))) void*)l, 16, 0, 0);
}

#define MFMA16(a, b, c) __builtin_amdgcn_mfma_f32_16x16x32_bf16(a, b, c, 0, 0, 0)

// ---------------------------------------------------------------------------
// prep: blocks [0,2048) convert x -> bf16 (2 float4/thread); blocks
// [2048,2304) transpose the four weight matrices to n-major bf16 (64x64).
// ---------------------------------------------------------------------------
__global__ __launch_bounds__(256) void prep(
    const float* __restrict__ x,
    const float* __restrict__ w0, const float* __restrict__ w1,
    const float* __restrict__ w2, const float* __restrict__ w3,
    ushort* __restrict__ xb, ushort* __restrict__ dst012,
    ushort* __restrict__ dst3)
{
    const int id = blockIdx.x;
    if (id < 2048) {
        const int j = id * 256 + threadIdx.x;
#pragma unroll
        for (int half = 0; half < 2; ++half) {
            const int i = j + half * 524288;
            float4 f = ((const float4*)x)[i];
            ushort4 u;
            u.x = f2b(f.x); u.y = f2b(f.y); u.z = f2b(f.z); u.w = f2b(f.w);
            ((ushort4*)xb)[i] = u;
        }
    } else {
        __shared__ float s[64][68];
        const int id2 = id - 2048;
        const int z = id2 >> 6, t = id2 & 63;
        const float* src = (z == 0) ? w0 : (z == 1) ? w1 : (z == 2) ? w2 : w3;
        ushort* dst = (z < 3) ? dst012 + (size_t)z * 512 * 512 : dst3;
        const int n0 = (t & 7) * 64, k0 = (t >> 3) * 64;
        const int tx = threadIdx.x & 15, ty = threadIdx.x >> 4;
#pragma unroll
        for (int p = 0; p < 4; ++p)
            *(float4*)&s[ty + 16 * p][tx * 4] =
                *(const float4*)&src[(size_t)(k0 + ty + 16 * p) * 512 + n0 + tx * 4];
        __syncthreads();
#pragma unroll
        for (int p = 0; p < 4; ++p) {
            ushort4 u;
            u.x = f2b(s[tx * 4 + 0][ty + 16 * p]);
            u.y = f2b(s[tx * 4 + 1][ty + 16 * p]);
            u.z = f2b(s[tx * 4 + 2][ty + 16 * p]);
            u.w = f2b(s[tx * 4 + 3][ty + 16 * p]);
            *(ushort4*)&dst[(size_t)(n0 + ty + 16 * p) * 512 + k0 + tx * 4] = u;
        }
    }
}

// ---------------------------------------------------------------------------
// QKV GEMM (R11-proven: 128x128 tiles, BK=64 via two 32-k planes, staged
// via global_load_lds w=16).  1-D grid, lin = col*64 + row -> A-stripe
// sharers co-XCD.  Epilogue: LDS repack, 16B stores; q,k scaled 0.125;
// V also written transposed to vT[((b*8+h)*64+d)*2048 + n].
// ---------------------------------------------------------------------------
__global__ __launch_bounds__(256) void gemm_qkv(
    const ushort* __restrict__ A, const ushort* __restrict__ Bt,
    ushort* __restrict__ oq, ushort* __restrict__ ok, ushort* __restrict__ ov,
    ushort* __restrict__ vT)
{
    __shared__ ushort Sbuf[4 * 128 * 32];   // As[2] | Bs[2]
    ushort* As = Sbuf;
    ushort* Bs = Sbuf + 2 * 128 * 32;
    const int tid  = threadIdx.x;
    const int rowB = (blockIdx.x & 63) * 128;
    const int colB = (blockIdx.x >> 6) * 128;
    const int wave = tid >> 6, lane = tid & 63;
    const int wm = wave & 1, wn = wave >> 1;
    const int l15 = lane & 15, quad = lane >> 4;

    f32x4 acc[4][4] = {};

    for (int kt = 0; kt < 512; kt += 64) {
#pragma unroll
        for (int pl = 0; pl < 2; ++pl)
#pragma unroll
            for (int p = 0; p < 2; ++p) {
                const int c = p * 256 + tid;
                const int row = c >> 2, sc = (c & 3) * 8;
                async16(A  + (size_t)(rowB + row) * 512 + kt + pl * 32 + sc,
                        &As[pl * 4096 + c * 8]);
                async16(Bt + (size_t)(colB + row) * 512 + kt + pl * 32 + sc,
                        &Bs[pl * 4096 + c * 8]);
            }
        __syncthreads();

#pragma unroll
        for (int pl = 0; pl < 2; ++pl) {
            short8 af[4], bf[4];
#pragma unroll
            for (int mi = 0; mi < 4; ++mi)
                af[mi] = *(const short8*)&As[pl * 4096 +
                          (wm * 64 + mi * 16 + l15) * 32 + quad * 8];
#pragma unroll
            for (int ni = 0; ni < 4; ++ni)
                bf[ni] = *(const short8*)&Bs[pl * 4096 +
                          (wn * 64 + ni * 16 + l15) * 32 + quad * 8];
#pragma unroll
            for (int mi = 0; mi < 4; ++mi)
#pragma unroll
                for (int ni = 0; ni < 4; ++ni)
                    acc[mi][ni] = MFMA16(af[mi], bf[ni], acc[mi][ni]);
        }
        __syncthreads();
    }
    // Sbuf dead -> per-wave repack regions.

    ushort* T = Sbuf + wave * 2048;      // 16 rows x stride 72
    const int sec = colB >> 9;           // block-uniform
    const float s = (sec == 2) ? 1.0f : 0.125f;
    const int cb = (colB & 511) + wn * 64;
#pragma unroll
    for (int mi = 0; mi < 4; ++mi) {
#pragma unroll
        for (int ni = 0; ni < 4; ++ni)
#pragma unroll
            for (int r = 0; r < 4; ++r)
                T[(quad * 4 + r) * 72 + ni * 16 + l15] = f2b(acc[mi][ni][r] * s);
        ushort* dst = (sec == 0) ? oq : (sec == 1) ? ok : ov;
#pragma unroll
        for (int u = 0; u < 2; ++u) {
            const int cid = lane * 2 + u;
            const int row = cid >> 3, ch = cid & 7;
            const int grow = rowB + wm * 64 + mi * 16 + row;
            *(short8*)&dst[(size_t)grow * HH + cb + ch * 8] =
                *(const short8*)&T[row * 72 + ch * 8];
        }
        if (sec == 2) {
            const int hh = cb >> 6;
            const int bb = rowB >> 11;
            const int nn0 = (rowB & 2047) + wm * 64 + mi * 16;
            ushort* vbase = vT + ((size_t)(bb * HEADS + hh) * HID) * NSEQ + nn0;
#pragma unroll
            for (int u = 0; u < 2; ++u) {
                short8 val;
#pragma unroll
                for (int j = 0; j < 8; ++j) val[j] = T[(u * 8 + j) * 72 + lane];
                *(short8*)(vbase + (size_t)lane * NSEQ + u * 8) = val;
            }
        }
    }
}

// ---------------------------------------------------------------------------
// Unify GEMM: 64x64 tiles, staged (R11-proven).  +bias, fp32 out.
// ---------------------------------------------------------------------------
__global__ __launch_bounds__(256) void gemm_unify(
    const ushort* __restrict__ A, const ushort* __restrict__ Bt,
    const float* __restrict__ bias, float* __restrict__ out)
{
    __shared__ ushort Sbuf[8192];
    __shared__ ushort Sbuf2[8192];
    ushort* As = Sbuf;
    ushort* Bs = Sbuf + 64 * 32;
    const int tid  = threadIdx.x;
    const int rowB = (blockIdx.x & 127) * 64;
    const int colB = (blockIdx.x >> 7) * 64;
    const int wave = tid >> 6, lane = tid & 63;
    const int wm = wave & 1, wn = wave >> 1;
    const int l15 = lane & 15, quad = lane >> 4;

    f32x4 acc[2][2] = {};

    for (int kt = 0; kt < 512; kt += 32) {
        {
            const int row = tid >> 2, sc = (tid & 3) * 8;
            async16(A  + (size_t)(rowB + row) * 512 + kt + sc, &As[tid * 8]);
            async16(Bt + (size_t)(colB + row) * 512 + kt + sc, &Bs[tid * 8]);
        }
        __syncthreads();

        short8 af[2], bf[2];
#pragma unroll
        for (int mi = 0; mi < 2; ++mi)
            af[mi] = *(const short8*)&As[(wm * 32 + mi * 16 + l15) * 32 + quad * 8];
#pragma unroll
        for (int ni = 0; ni < 2; ++ni)
            bf[ni] = *(const short8*)&Bs[(wn * 32 + ni * 16 + l15) * 32 + quad * 8];
#pragma unroll
        for (int mi = 0; mi < 2; ++mi)
#pragma unroll
            for (int ni = 0; ni < 2; ++ni)
                acc[mi][ni] = MFMA16(af[mi], bf[ni], acc[mi][ni]);
        __syncthreads();
    }

    float* Tf = (float*)((wave & 1) ? Sbuf2 : Sbuf) + (wave >> 1) * 1024;
    float bcol[2];
#pragma unroll
    for (int ni = 0; ni < 2; ++ni)
        bcol[ni] = bias[colB + wn * 32 + ni * 16 + l15];
#pragma unroll
    for (int mi = 0; mi < 2; ++mi)
#pragma unroll
        for (int ni = 0; ni < 2; ++ni)
#pragma unroll
            for (int r = 0; r < 4; ++r)
                Tf[(mi * 16 + quad * 4 + r) * 32 + ni * 16 + l15] =
                    acc[mi][ni][r] + bcol[ni];
#pragma unroll
    for (int u = 0; u < 4; ++u) {
        const int cid = lane * 4 + u;
        const int row = cid >> 3, ch = cid & 7;
        *(float4*)&out[(size_t)(rowB + wm * 32 + row) * EMB + colB + wn * 32 + ch * 4] =
            *(const float4*)&Tf[row * 32 + ch * 4];
    }
}

// ---------------------------------------------------------------------------
// Kernel B: strided attention in RESIDUE space (unchanged from R10).
// ---------------------------------------------------------------------------
__global__ __launch_bounds__(64) void attn_str(
    const ushort* __restrict__ q, const ushort* __restrict__ k,
    const ushort* __restrict__ v, ushort* __restrict__ obn,
    float* __restrict__ mbuf, float* __restrict__ sbuf)
{
    const int slice = blockIdx.x & 31;     // h + 8*b
    const int r     = blockIdx.x >> 5;     // residue 0..63
    const int h = slice & 7, b = slice >> 3;
    const int lane = threadIdx.x, l15 = lane & 15, quad = lane >> 4;
    const ptrdiff_t rowb = (ptrdiff_t)b * NSEQ;
    const int hb = h * HID;

    __shared__ union {
        struct { ushort Ps[32][40]; ushort Vt[64][40]; } s;
        float Ot[32][66];
    } U;

    {
        const int dg = lane & 7, g = lane >> 3;
#pragma unroll
        for (int p = 0; p < 4; ++p) {
            const int i = p * 8 + g;
            const short8 vv = *(const short8*)(
                v + (rowb + r + 64 * i) * 512 + hb + dg * 8);
#pragma unroll
            for (int e = 0; e < 8; ++e) {
                const int m = (e + dg) & 7;
                U.s.Vt[dg * 8 + m][i] = (ushort)vv[m];
            }
        }
    }
    { ushort4 z = {0, 0, 0, 0}; *(ushort4*)&U.s.Ps[l15][16 + quad * 4] = z; }

    short8 aq[2][2], bk[2][2];
#pragma unroll
    for (int t = 0; t < 2; ++t) {
        const ushort* p = q + (rowb + r + 64 * (t * 16 + l15)) * 512 + hb + quad * 8;
        aq[t][0] = *(const short8*)p;
        aq[t][1] = *(const short8*)(p + 32);
        const ushort* pk = k + (rowb + r + 64 * (t * 16 + l15)) * 512 + hb + quad * 8;
        bk[t][0] = *(const short8*)pk;
        bk[t][1] = *(const short8*)(pk + 32);
    }
    f32x4 s00 = {}, s10 = {}, s11 = {};
    s00 = MFMA16(aq[0][0], bk[0][0], s00); s00 = MFMA16(aq[0][1], bk[0][1], s00);
    s10 = MFMA16(aq[1][0], bk[0][0], s10); s10 = MFMA16(aq[1][1], bk[0][1], s10);
    s11 = MFMA16(aq[1][0], bk[1][0], s11); s11 = MFMA16(aq[1][1], bk[1][1], s11);

    float rsB[2][4];
#pragma unroll
    for (int t = 0; t < 2; ++t)
#pragma unroll
        for (int rg = 0; rg < 4; ++rg) {
            const int i = t * 16 + quad * 4 + rg;
            float v0 = (t == 0) ? s00[rg] : s10[rg];
            float v1 = (t == 1) ? s11[rg] : -1e30f;
            if (l15 > i - 2) v0 = -1e30f;
            if (t == 1 && 16 + l15 > i - 2) v1 = -1e30f;
            float mx = fmaxf(v0, v1);
            mx = fmaxf(mx, __shfl_xor(mx, 1)); mx = fmaxf(mx, __shfl_xor(mx, 2));
            mx = fmaxf(mx, __shfl_xor(mx, 4)); mx = fmaxf(mx, __shfl_xor(mx, 8));
            const float e0 = __expf(v0 - mx);
            const float e1 = (t == 1) ? __expf(v1 - mx) : 0.f;
            float sum = e0 + e1;
            sum += __shfl_xor(sum, 1); sum += __shfl_xor(sum, 2);
            sum += __shfl_xor(sum, 4); sum += __shfl_xor(sum, 8);
            U.s.Ps[i][l15] = f2b(e0);
            if (t == 1) U.s.Ps[i][16 + l15] = f2b(e1);
            rsB[t][rg] = 1.0f / sum;
            if (l15 == 0 && i >= 2) {
                mbuf[(size_t)slice * NSEQ + r + 64 * i] = mx;
                sbuf[(size_t)slice * NSEQ + r + 64 * i] = sum;
            }
        }

    short8 ap[2], bp[4];
#pragma unroll
    for (int t = 0; t < 2; ++t)
        ap[t] = *(const short8*)&U.s.Ps[t * 16 + l15][quad * 8];
#pragma unroll
    for (int nt = 0; nt < 4; ++nt)
        bp[nt] = *(const short8*)&U.s.Vt[nt * 16 + l15][quad * 8];
    f32x4 O[2][4] = {};
#pragma unroll
    for (int t = 0; t < 2; ++t)
#pragma unroll
        for (int nt = 0; nt < 4; ++nt)
            O[t][nt] = MFMA16(ap[t], bp[nt], O[t][nt]);

#pragma unroll
    for (int t = 0; t < 2; ++t)
#pragma unroll
        for (int nt = 0; nt < 4; ++nt)
#pragma unroll
            for (int rg = 0; rg < 4; ++rg)
                U.Ot[t * 16 + quad * 4 + rg][nt * 16 + l15] = O[t][nt][rg] * rsB[t][rg];
    for (int i = 2; i < 32; ++i)
        obn[(rowb + r + 64 * i) * 512 + hb + lane] = f2b(U.Ot[i][lane]);
}

// ---------------------------------------------------------------------------
// Kernel A: local-band attention + flash-merge (R11-proven 16q version).
// ---------------------------------------------------------------------------
struct __align__(16) WaveWS {
    union { ushort Ps[16][112]; float Ot[16][66]; } u;
    float ca[16], cb[16];
};

__global__ __launch_bounds__(64) void attn_band(
    const ushort* __restrict__ q, const ushort* __restrict__ k,
    const ushort* __restrict__ vT, const ushort* __restrict__ obn,
    const float* __restrict__ mbuf, const float* __restrict__ sbuf,
    ushort* __restrict__ o)
{
    const int slice = blockIdx.x & 31;
    const int qidx  = blockIdx.x >> 5;
    const int h = slice & 7, b = slice >> 3;
    const int lane = threadIdx.x;
    const int l15 = lane & 15, quad = lane >> 4;
    const int qw = qidx * 16;
    const int qb = qw >> 6;
    const int band0 = qw - 64;

    __shared__ WaveWS S;

    const ptrdiff_t rowb = (ptrdiff_t)b * NSEQ;
    const int hb = h * HID;

    { ushort4 z = {0, 0, 0, 0}; *(ushort4*)&S.u.Ps[l15][80 + quad * 4] = z; }

    short8 afq[2];
    {
        const ushort* qp = q + (rowb + qw + l15) * 512 + hb + quad * 8;
        afq[0] = *(const short8*)qp;
        afq[1] = *(const short8*)(qp + 32);
    }

    f32x4 accL[5];
#pragma unroll
    for (int kt = 0; kt < 5; ++kt) {
        accL[kt] = (f32x4){0.f, 0.f, 0.f, 0.f};
        const ushort* kp = k + (rowb + band0 + kt * 16 + l15) * 512 + hb + quad * 8;
        const short8 b0 = *(const short8*)kp;
        const short8 b1 = *(const short8*)(kp + 32);
        accL[kt] = MFMA16(afq[0], b0, accL[kt]);
        accL[kt] = MFMA16(afq[1], b1, accL[kt]);
    }

#pragma unroll
    for (int rg = 0; rg < 4; ++rg) {
        const int row16 = quad * 4 + rg;
        float pm[5], mx = -1e30f;
#pragma unroll
        for (int kt = 0; kt < 5; ++kt) {
            const int col = kt * 16 + l15;
            const bool okm = (col >= row16) && (col <= 64 + row16) && (band0 + col >= 0);
            pm[kt] = okm ? accL[kt][rg] : -1e30f;
            mx = fmaxf(mx, pm[kt]);
        }
        mx = fmaxf(mx, __shfl_xor(mx, 1)); mx = fmaxf(mx, __shfl_xor(mx, 2));
        mx = fmaxf(mx, __shfl_xor(mx, 4)); mx = fmaxf(mx, __shfl_xor(mx, 8));
        float sum = 0.f;
#pragma unroll
        for (int kt = 0; kt < 5; ++kt) {
            const float pv = __expf(pm[kt] - mx);
            sum += pv;
            S.u.Ps[row16][kt * 16 + l15] = f2b(pv);
        }
        sum += __shfl_xor(sum, 1); sum += __shfl_xor(sum, 2);
        sum += __shfl_xor(sum, 4); sum += __shfl_xor(sum, 8);
        if (l15 == 0) {
            if (qb >= 2) {
                const float mB = mbuf[(size_t)slice * NSEQ + qw + row16];
                const float sB = sbuf[(size_t)slice * NSEQ + qw + row16];
                const float m  = fmaxf(mx, mB);
                const float eA = __expf(mx - m), eB = __expf(mB - m);
                const float denom = sum * eA + sB * eB;
                S.ca[row16] = eA / denom;
                S.cb[row16] = sB * eB / denom;
            } else {
                S.ca[row16] = 1.0f / sum;
                S.cb[row16] = 0.f;
            }
        }
    }

    f32x4 O[4];
#pragma unroll
    for (int nt = 0; nt < 4; ++nt) O[nt] = (f32x4){0.f, 0.f, 0.f, 0.f};
    const ushort* vtb = vT + ((ptrdiff_t)(b * HEADS + h) * HID) * NSEQ;
#pragma unroll
    for (int ks = 0; ks < 3; ++ks) {
        const short8 ap = *(const short8*)&S.u.Ps[l15][ks * 32 + quad * 8];
#pragma unroll
        for (int nt = 0; nt < 4; ++nt) {
            const short8 bp = *(const short8*)(
                vtb + (ptrdiff_t)(nt * 16 + l15) * NSEQ + band0 + ks * 32 + quad * 8);
            O[nt] = MFMA16(ap, bp, O[nt]);
        }
    }

#pragma unroll
    for (int nt = 0; nt < 4; ++nt)
#pragma unroll
        for (int rg = 0; rg < 4; ++rg)
            S.u.Ot[quad * 4 + rg][nt * 16 + l15] = O[nt][rg];

    if (qb >= 2) {
#pragma unroll 4
        for (int i2 = 0; i2 < 16; ++i2) {
            const ptrdiff_t off = (rowb + qw + i2) * 512 + hb + lane;
            const float val = S.u.Ot[i2][lane] * S.ca[i2] + b2f(obn[off]) * S.cb[i2];
            o[off] = f2b(val);
        }
    } else {
#pragma unroll 4
        for (int i2 = 0; i2 < 16; ++i2) {
            const ptrdiff_t off = (rowb + qw + i2) * 512 + hb + lane;
            o[off] = f2b(S.u.Ot[i2][lane] * S.ca[i2]);
        }
    }
}

// ---------------------------------------------------------------------------
extern "C" void kernel_launch(void* const* d_in, const int* in_sizes, int n_in,
                              void* d_out, int out_size, void* d_ws, size_t ws_size,
                              hipStream_t stream)
{
    // dict order: x, w_keys, w_queries, w_values, w_unify, b_unify (fp32)
    const float* x  = (const float*)d_in[0];
    const float* wk = (const float*)d_in[1];
    const float* wq = (const float*)d_in[2];
    const float* wv = (const float*)d_in[3];
    const float* wu = (const float*)d_in[4];
    const float* bu = (const float*)d_in[5];
    float* out = (float*)d_out;

    // ws: xb 8M | wbt 1.5M | wubt .5M | ob 8M | qb 8M | kb 8M | vT 8M | vb 8M
    //     | obn 8M | mbuf .25M | sbuf .25M
    ushort* xb   = (ushort*)d_ws;
    ushort* wbt  = xb   + (size_t)ROWS * EMB;
    ushort* wubt = wbt  + (size_t)1536 * 512;
    ushort* ob   = wubt + (size_t)512 * 512;
    ushort* qbuf = ob   + (size_t)ROWS * HH;
    ushort* kbuf = qbuf + (size_t)ROWS * HH;
    ushort* vTb  = kbuf + (size_t)ROWS * HH;
    ushort* vbuf = vTb  + (size_t)ROWS * HH;
    ushort* obn  = vbuf + (size_t)ROWS * HH;
    float*  mbuf = (float*)(obn + (size_t)ROWS * HH);
    float*  sbuf = mbuf + (size_t)32 * NSEQ;

    prep<<<2304, 256, 0, stream>>>(x, wq, wk, wv, wu, xb, wbt, wubt);
    gemm_qkv<<<12 * 64, 256, 0, stream>>>(xb, wbt, qbuf, kbuf, vbuf, vTb);
    attn_str<<<64 * 32, 64, 0, stream>>>(qbuf, kbuf, vbuf, obn, mbuf, sbuf);
    attn_band<<<128 * 32, 64, 0, stream>>>(qbuf, kbuf, vTb, obn, mbuf, sbuf, ob);
    gemm_unify<<<8 * 128, 256, 0, stream>>>(ob, wubt, bu, out);
}

// Round 16
// 140.302 us; speedup vs baseline: 1.2895x; 1.0184x over previous
//
#include <hip/hip_runtime.h>
#include <hip/hip_bf16.h>

#define HEADS 8
#define HID   64
#define EMB   512
#define HH    512
#define LOCAL 64
#define BS    4
#define NSEQ  2048
#define ROWS  (BS*NSEQ)   // 8192

typedef __attribute__((ext_vector_type(8))) short short8;   // 8 bf16 = 4 VGPRs
typedef __attribute__((ext_vector_type(4))) float f32x4;

__device__ __forceinline__ ushort f2b(float f) {
    union { float f; unsigned u; } c; c.f = f;
    return (ushort)((c.u + 0x7FFFu + ((c.u >> 16) & 1u)) >> 16);
}
__device__ __forceinline__ float b2f(ushort u) {
    union { unsigned u; float f; } c; c.u = ((unsigned)u) << 16; return c.f;
}

__device__ __forceinline__ void async16(const void* g, void* l) {
    __builtin_amdgcn_global_load_lds(
        (const __attribute__((address_space(1))) void*)g,
        (__attribute__((address_space(3))) void*)l, 16, 0, 0);
}

#define MFMA16(a, b, c) __builtin_amdgcn_mfma_f32_16x16x32_bf16(a, b, c, 0, 0, 0)

// ---------------------------------------------------------------------------
// prep: blocks [0,4096) convert x -> bf16; blocks [4096,8192) transpose the
// four weight matrices to n-major bf16.  (R11 version — 16x17 LDS tile is
// bank-conflict-free; the 64x68 fp32 variant measured ~2.5us slower.)
// ---------------------------------------------------------------------------
__global__ __launch_bounds__(256) void prep(
    const float* __restrict__ x,
    const float* __restrict__ w0, const float* __restrict__ w1,
    const float* __restrict__ w2, const float* __restrict__ w3,
    ushort* __restrict__ xb, ushort* __restrict__ dst012,
    ushort* __restrict__ dst3)
{
    __shared__ float s[16][17];
    const int id = blockIdx.x;
    if (id < 4096) {
        const int i = id * 256 + threadIdx.x;
        float4 f = ((const float4*)x)[i];
        ushort4 u;
        u.x = f2b(f.x); u.y = f2b(f.y); u.z = f2b(f.z); u.w = f2b(f.w);
        ((ushort4*)xb)[i] = u;
    } else {
        const int id2 = id - 4096;
        const int z = id2 >> 10, t = id2 & 1023;
        const float* src = (z == 0) ? w0 : (z == 1) ? w1 : (z == 2) ? w2 : w3;
        ushort* dst = (z < 3) ? dst012 + (size_t)z * 512 * 512 : dst3;
        const int n0 = (t & 31) * 16, k0 = (t >> 5) * 16;
        const int tx = threadIdx.x & 15, ty = threadIdx.x >> 4;
        s[ty][tx] = src[(size_t)(k0 + ty) * 512 + n0 + tx];
        __syncthreads();
        dst[(size_t)(n0 + ty) * 512 + k0 + tx] = f2b(s[tx][ty]);
    }
}

// ---------------------------------------------------------------------------
// QKV GEMM: 128x128 tiles, BK=64 via two 32-k planes (m97 staging).  1-D
// grid, lin = col*64 + row -> A-stripe sharers co-XCD.  Epilogue: LDS
// repack, 16B stores; q,k scaled 0.125; V also written transposed to
// vT[((b*8+h)*64+d)*2048 + n].
// ---------------------------------------------------------------------------
__global__ __launch_bounds__(256) void gemm_qkv(
    const ushort* __restrict__ A, const ushort* __restrict__ Bt,
    ushort* __restrict__ oq, ushort* __restrict__ ok, ushort* __restrict__ ov,
    ushort* __restrict__ vT)
{
    __shared__ ushort Sbuf[4 * 128 * 32];   // As[2] | Bs[2]
    ushort* As = Sbuf;
    ushort* Bs = Sbuf + 2 * 128 * 32;
    const int tid  = threadIdx.x;
    const int rowB = (blockIdx.x & 63) * 128;
    const int colB = (blockIdx.x >> 6) * 128;
    const int wave = tid >> 6, lane = tid & 63;
    const int wm = wave & 1, wn = wave >> 1;
    const int l15 = lane & 15, quad = lane >> 4;

    f32x4 acc[4][4] = {};

    for (int kt = 0; kt < 512; kt += 64) {
#pragma unroll
        for (int pl = 0; pl < 2; ++pl)
#pragma unroll
            for (int p = 0; p < 2; ++p) {
                const int c = p * 256 + tid;
                const int row = c >> 2, sc = (c & 3) * 8;
                async16(A  + (size_t)(rowB + row) * 512 + kt + pl * 32 + sc,
                        &As[pl * 4096 + c * 8]);
                async16(Bt + (size_t)(colB + row) * 512 + kt + pl * 32 + sc,
                        &Bs[pl * 4096 + c * 8]);
            }
        __syncthreads();

#pragma unroll
        for (int pl = 0; pl < 2; ++pl) {
            short8 af[4], bf[4];
#pragma unroll
            for (int mi = 0; mi < 4; ++mi)
                af[mi] = *(const short8*)&As[pl * 4096 +
                          (wm * 64 + mi * 16 + l15) * 32 + quad * 8];
#pragma unroll
            for (int ni = 0; ni < 4; ++ni)
                bf[ni] = *(const short8*)&Bs[pl * 4096 +
                          (wn * 64 + ni * 16 + l15) * 32 + quad * 8];
#pragma unroll
            for (int mi = 0; mi < 4; ++mi)
#pragma unroll
                for (int ni = 0; ni < 4; ++ni)
                    acc[mi][ni] = MFMA16(af[mi], bf[ni], acc[mi][ni]);
        }
        __syncthreads();
    }
    // Sbuf dead -> per-wave repack regions.

    ushort* T = Sbuf + wave * 2048;      // 16 rows x stride 72
    const int sec = colB >> 9;           // block-uniform
    const float s = (sec == 2) ? 1.0f : 0.125f;
    const int cb = (colB & 511) + wn * 64;
#pragma unroll
    for (int mi = 0; mi < 4; ++mi) {
#pragma unroll
        for (int ni = 0; ni < 4; ++ni)
#pragma unroll
            for (int r = 0; r < 4; ++r)
                T[(quad * 4 + r) * 72 + ni * 16 + l15] = f2b(acc[mi][ni][r] * s);
        ushort* dst = (sec == 0) ? oq : (sec == 1) ? ok : ov;
#pragma unroll
        for (int u = 0; u < 2; ++u) {
            const int cid = lane * 2 + u;
            const int row = cid >> 3, ch = cid & 7;
            const int grow = rowB + wm * 64 + mi * 16 + row;
            *(short8*)&dst[(size_t)grow * HH + cb + ch * 8] =
                *(const short8*)&T[row * 72 + ch * 8];
        }
        if (sec == 2) {
            const int hh = cb >> 6;
            const int bb = rowB >> 11;
            const int nn0 = (rowB & 2047) + wm * 64 + mi * 16;
            ushort* vbase = vT + ((size_t)(bb * HEADS + hh) * HID) * NSEQ + nn0;
#pragma unroll
            for (int u = 0; u < 2; ++u) {
                short8 val;
#pragma unroll
                for (int j = 0; j < 8; ++j) val[j] = T[(u * 8 + j) * 72 + lane];
                *(short8*)(vbase + (size_t)lane * NSEQ + u * 8) = val;
            }
        }
    }
}

// ---------------------------------------------------------------------------
// Unify GEMM: 64x64 tiles, staged.  +bias, fp32 out.
// ---------------------------------------------------------------------------
__global__ __launch_bounds__(256) void gemm_unify(
    const ushort* __restrict__ A, const ushort* __restrict__ Bt,
    const float* __restrict__ bias, float* __restrict__ out)
{
    __shared__ ushort Sbuf[8192];
    __shared__ ushort Sbuf2[8192];
    ushort* As = Sbuf;
    ushort* Bs = Sbuf + 64 * 32;
    const int tid  = threadIdx.x;
    const int rowB = (blockIdx.x & 127) * 64;
    const int colB = (blockIdx.x >> 7) * 64;
    const int wave = tid >> 6, lane = tid & 63;
    const int wm = wave & 1, wn = wave >> 1;
    const int l15 = lane & 15, quad = lane >> 4;

    f32x4 acc[2][2] = {};

    for (int kt = 0; kt < 512; kt += 32) {
        {
            const int row = tid >> 2, sc = (tid & 3) * 8;
            async16(A  + (size_t)(rowB + row) * 512 + kt + sc, &As[tid * 8]);
            async16(Bt + (size_t)(colB + row) * 512 + kt + sc, &Bs[tid * 8]);
        }
        __syncthreads();

        short8 af[2], bf[2];
#pragma unroll
        for (int mi = 0; mi < 2; ++mi)
            af[mi] = *(const short8*)&As[(wm * 32 + mi * 16 + l15) * 32 + quad * 8];
#pragma unroll
        for (int ni = 0; ni < 2; ++ni)
            bf[ni] = *(const short8*)&Bs[(wn * 32 + ni * 16 + l15) * 32 + quad * 8];
#pragma unroll
        for (int mi = 0; mi < 2; ++mi)
#pragma unroll
            for (int ni = 0; ni < 2; ++ni)
                acc[mi][ni] = MFMA16(af[mi], bf[ni], acc[mi][ni]);
        __syncthreads();
    }

    float* Tf = (float*)((wave & 1) ? Sbuf2 : Sbuf) + (wave >> 1) * 1024;
    float bcol[2];
#pragma unroll
    for (int ni = 0; ni < 2; ++ni)
        bcol[ni] = bias[colB + wn * 32 + ni * 16 + l15];
#pragma unroll
    for (int mi = 0; mi < 2; ++mi)
#pragma unroll
        for (int ni = 0; ni < 2; ++ni)
#pragma unroll
            for (int r = 0; r < 4; ++r)
                Tf[(mi * 16 + quad * 4 + r) * 32 + ni * 16 + l15] =
                    acc[mi][ni][r] + bcol[ni];
#pragma unroll
    for (int u = 0; u < 4; ++u) {
        const int cid = lane * 4 + u;
        const int row = cid >> 3, ch = cid & 7;
        *(float4*)&out[(size_t)(rowB + wm * 32 + row) * EMB + colB + wn * 32 + ch * 4] =
            *(const float4*)&Tf[row * 32 + ch * 4];
    }
}

// ---------------------------------------------------------------------------
// Kernel B: strided attention in RESIDUE space.
// ---------------------------------------------------------------------------
__global__ __launch_bounds__(64) void attn_str(
    const ushort* __restrict__ q, const ushort* __restrict__ k,
    const ushort* __restrict__ v, ushort* __restrict__ obn,
    float* __restrict__ mbuf, float* __restrict__ sbuf)
{
    const int slice = blockIdx.x & 31;     // h + 8*b
    const int r     = blockIdx.x >> 5;     // residue 0..63
    const int h = slice & 7, b = slice >> 3;
    const int lane = threadIdx.x, l15 = lane & 15, quad = lane >> 4;
    const ptrdiff_t rowb = (ptrdiff_t)b * NSEQ;
    const int hb = h * HID;

    __shared__ union {
        struct { ushort Ps[32][40]; ushort Vt[64][40]; } s;
        float Ot[32][66];
    } U;

    {
        const int dg = lane & 7, g = lane >> 3;
#pragma unroll
        for (int p = 0; p < 4; ++p) {
            const int i = p * 8 + g;
            const short8 vv = *(const short8*)(
                v + (rowb + r + 64 * i) * 512 + hb + dg * 8);
#pragma unroll
            for (int e = 0; e < 8; ++e) {
                const int m = (e + dg) & 7;
                U.s.Vt[dg * 8 + m][i] = (ushort)vv[m];
            }
        }
    }
    { ushort4 z = {0, 0, 0, 0}; *(ushort4*)&U.s.Ps[l15][16 + quad * 4] = z; }

    short8 aq[2][2], bk[2][2];
#pragma unroll
    for (int t = 0; t < 2; ++t) {
        const ushort* p = q + (rowb + r + 64 * (t * 16 + l15)) * 512 + hb + quad * 8;
        aq[t][0] = *(const short8*)p;
        aq[t][1] = *(const short8*)(p + 32);
        const ushort* pk = k + (rowb + r + 64 * (t * 16 + l15)) * 512 + hb + quad * 8;
        bk[t][0] = *(const short8*)pk;
        bk[t][1] = *(const short8*)(pk + 32);
    }
    f32x4 s00 = {}, s10 = {}, s11 = {};
    s00 = MFMA16(aq[0][0], bk[0][0], s00); s00 = MFMA16(aq[0][1], bk[0][1], s00);
    s10 = MFMA16(aq[1][0], bk[0][0], s10); s10 = MFMA16(aq[1][1], bk[0][1], s10);
    s11 = MFMA16(aq[1][0], bk[1][0], s11); s11 = MFMA16(aq[1][1], bk[1][1], s11);

    float rsB[2][4];
#pragma unroll
    for (int t = 0; t < 2; ++t)
#pragma unroll
        for (int rg = 0; rg < 4; ++rg) {
            const int i = t * 16 + quad * 4 + rg;
            float v0 = (t == 0) ? s00[rg] : s10[rg];
            float v1 = (t == 1) ? s11[rg] : -1e30f;
            if (l15 > i - 2) v0 = -1e30f;
            if (t == 1 && 16 + l15 > i - 2) v1 = -1e30f;
            float mx = fmaxf(v0, v1);
            mx = fmaxf(mx, __shfl_xor(mx, 1)); mx = fmaxf(mx, __shfl_xor(mx, 2));
            mx = fmaxf(mx, __shfl_xor(mx, 4)); mx = fmaxf(mx, __shfl_xor(mx, 8));
            const float e0 = __expf(v0 - mx);
            const float e1 = (t == 1) ? __expf(v1 - mx) : 0.f;
            float sum = e0 + e1;
            sum += __shfl_xor(sum, 1); sum += __shfl_xor(sum, 2);
            sum += __shfl_xor(sum, 4); sum += __shfl_xor(sum, 8);
            U.s.Ps[i][l15] = f2b(e0);
            if (t == 1) U.s.Ps[i][16 + l15] = f2b(e1);
            rsB[t][rg] = 1.0f / sum;
            if (l15 == 0 && i >= 2) {
                mbuf[(size_t)slice * NSEQ + r + 64 * i] = mx;
                sbuf[(size_t)slice * NSEQ + r + 64 * i] = sum;
            }
        }

    short8 ap[2], bp[4];
#pragma unroll
    for (int t = 0; t < 2; ++t)
        ap[t] = *(const short8*)&U.s.Ps[t * 16 + l15][quad * 8];
#pragma unroll
    for (int nt = 0; nt < 4; ++nt)
        bp[nt] = *(const short8*)&U.s.Vt[nt * 16 + l15][quad * 8];
    f32x4 O[2][4] = {};
#pragma unroll
    for (int t = 0; t < 2; ++t)
#pragma unroll
        for (int nt = 0; nt < 4; ++nt)
            O[t][nt] = MFMA16(ap[t], bp[nt], O[t][nt]);

#pragma unroll
    for (int t = 0; t < 2; ++t)
#pragma unroll
        for (int nt = 0; nt < 4; ++nt)
#pragma unroll
            for (int rg = 0; rg < 4; ++rg)
                U.Ot[t * 16 + quad * 4 + rg][nt * 16 + l15] = O[t][nt][rg] * rsB[t][rg];
    for (int i = 2; i < 32; ++i)
        obn[(rowb + r + 64 * i) * 512 + hb + lane] = f2b(U.Ot[i][lane]);
}

// ---------------------------------------------------------------------------
// Kernel A: local-band attention + flash-merge (16 queries/wave).
// ---------------------------------------------------------------------------
struct __align__(16) WaveWS {
    union { ushort Ps[16][112]; float Ot[16][66]; } u;
    float ca[16], cb[16];
};

__global__ __launch_bounds__(64) void attn_band(
    const ushort* __restrict__ q, const ushort* __restrict__ k,
    const ushort* __restrict__ vT, const ushort* __restrict__ obn,
    const float* __restrict__ mbuf, const float* __restrict__ sbuf,
    ushort* __restrict__ o)
{
    const int slice = blockIdx.x & 31;
    const int qidx  = blockIdx.x >> 5;
    const int h = slice & 7, b = slice >> 3;
    const int lane = threadIdx.x;
    const int l15 = lane & 15, quad = lane >> 4;
    const int qw = qidx * 16;
    const int qb = qw >> 6;
    const int band0 = qw - 64;

    __shared__ WaveWS S;

    const ptrdiff_t rowb = (ptrdiff_t)b * NSEQ;
    const int hb = h * HID;

    { ushort4 z = {0, 0, 0, 0}; *(ushort4*)&S.u.Ps[l15][80 + quad * 4] = z; }

    short8 afq[2];
    {
        const ushort* qp = q + (rowb + qw + l15) * 512 + hb + quad * 8;
        afq[0] = *(const short8*)qp;
        afq[1] = *(const short8*)(qp + 32);
    }

    f32x4 accL[5];
#pragma unroll
    for (int kt = 0; kt < 5; ++kt) {
        accL[kt] = (f32x4){0.f, 0.f, 0.f, 0.f};
        const ushort* kp = k + (rowb + band0 + kt * 16 + l15) * 512 + hb + quad * 8;
        const short8 b0 = *(const short8*)kp;
        const short8 b1 = *(const short8*)(kp + 32);
        accL[kt] = MFMA16(afq[0], b0, accL[kt]);
        accL[kt] = MFMA16(afq[1], b1, accL[kt]);
    }

#pragma unroll
    for (int rg = 0; rg < 4; ++rg) {
        const int row16 = quad * 4 + rg;
        float pm[5], mx = -1e30f;
#pragma unroll
        for (int kt = 0; kt < 5; ++kt) {
            const int col = kt * 16 + l15;
            const bool okm = (col >= row16) && (col <= 64 + row16) && (band0 + col >= 0);
            pm[kt] = okm ? accL[kt][rg] : -1e30f;
            mx = fmaxf(mx, pm[kt]);
        }
        mx = fmaxf(mx, __shfl_xor(mx, 1)); mx = fmaxf(mx, __shfl_xor(mx, 2));
        mx = fmaxf(mx, __shfl_xor(mx, 4)); mx = fmaxf(mx, __shfl_xor(mx, 8));
        float sum = 0.f;
#pragma unroll
        for (int kt = 0; kt < 5; ++kt) {
            const float pv = __expf(pm[kt] - mx);
            sum += pv;
            S.u.Ps[row16][kt * 16 + l15] = f2b(pv);
        }
        sum += __shfl_xor(sum, 1); sum += __shfl_xor(sum, 2);
        sum += __shfl_xor(sum, 4); sum += __shfl_xor(sum, 8);
        if (l15 == 0) {
            if (qb >= 2) {
                const float mB = mbuf[(size_t)slice * NSEQ + qw + row16];
                const float sB = sbuf[(size_t)slice * NSEQ + qw + row16];
                const float m  = fmaxf(mx, mB);
                const float eA = __expf(mx - m), eB = __expf(mB - m);
                const float denom = sum * eA + sB * eB;
                S.ca[row16] = eA / denom;
                S.cb[row16] = sB * eB / denom;
            } else {
                S.ca[row16] = 1.0f / sum;
                S.cb[row16] = 0.f;
            }
        }
    }

    f32x4 O[4];
#pragma unroll
    for (int nt = 0; nt < 4; ++nt) O[nt] = (f32x4){0.f, 0.f, 0.f, 0.f};
    const ushort* vtb = vT + ((ptrdiff_t)(b * HEADS + h) * HID) * NSEQ;
#pragma unroll
    for (int ks = 0; ks < 3; ++ks) {
        const short8 ap = *(const short8*)&S.u.Ps[l15][ks * 32 + quad * 8];
#pragma unroll
        for (int nt = 0; nt < 4; ++nt) {
            const short8 bp = *(const short8*)(
                vtb + (ptrdiff_t)(nt * 16 + l15) * NSEQ + band0 + ks * 32 + quad * 8);
            O[nt] = MFMA16(ap, bp, O[nt]);
        }
    }

#pragma unroll
    for (int nt = 0; nt < 4; ++nt)
#pragma unroll
        for (int rg = 0; rg < 4; ++rg)
            S.u.Ot[quad * 4 + rg][nt * 16 + l15] = O[nt][rg];

    if (qb >= 2) {
#pragma unroll 4
        for (int i2 = 0; i2 < 16; ++i2) {
            const ptrdiff_t off = (rowb + qw + i2) * 512 + hb + lane;
            const float val = S.u.Ot[i2][lane] * S.ca[i2] + b2f(obn[off]) * S.cb[i2];
            o[off] = f2b(val);
        }
    } else {
#pragma unroll 4
        for (int i2 = 0; i2 < 16; ++i2) {
            const ptrdiff_t off = (rowb + qw + i2) * 512 + hb + lane;
            o[off] = f2b(S.u.Ot[i2][lane] * S.ca[i2]);
        }
    }
}

// ---------------------------------------------------------------------------
extern "C" void kernel_launch(void* const* d_in, const int* in_sizes, int n_in,
                              void* d_out, int out_size, void* d_ws, size_t ws_size,
                              hipStream_t stream)
{
    // dict order: x, w_keys, w_queries, w_values, w_unify, b_unify (fp32)
    const float* x  = (const float*)d_in[0];
    const float* wk = (const float*)d_in[1];
    const float* wq = (const float*)d_in[2];
    const float* wv = (const float*)d_in[3];
    const float* wu = (const float*)d_in[4];
    const float* bu = (const float*)d_in[5];
    float* out = (float*)d_out;

    // ws: xb 8M | wbt 1.5M | wubt .5M | ob 8M | qb 8M | kb 8M | vT 8M | vb 8M
    //     | obn 8M | mbuf .25M | sbuf .25M
    ushort* xb   = (ushort*)d_ws;
    ushort* wbt  = xb   + (size_t)ROWS * EMB;
    ushort* wubt = wbt  + (size_t)1536 * 512;
    ushort* ob   = wubt + (size_t)512 * 512;
    ushort* qbuf = ob   + (size_t)ROWS * HH;
    ushort* kbuf = qbuf + (size_t)ROWS * HH;
    ushort* vTb  = kbuf + (size_t)ROWS * HH;
    ushort* vbuf = vTb  + (size_t)ROWS * HH;
    ushort* obn  = vbuf + (size_t)ROWS * HH;
    float*  mbuf = (float*)(obn + (size_t)ROWS * HH);
    float*  sbuf = mbuf + (size_t)32 * NSEQ;

    prep<<<8192, 256, 0, stream>>>(x, wq, wk, wv, wu, xb, wbt, wubt);
    gemm_qkv<<<12 * 64, 256, 0, stream>>>(xb, wbt, qbuf, kbuf, vbuf, vTb);
    attn_str<<<64 * 32, 64, 0, stream>>>(qbuf, kbuf, vbuf, obn, mbuf, sbuf);
    attn_band<<<128 * 32, 64, 0, stream>>>(qbuf, kbuf, vTb, obn, mbuf, sbuf, ob);
    gemm_unify<<<8 * 128, 256, 0, stream>>>(ob, wubt, bu, out);
}